// Round 6
// baseline (468.855 us; speedup 1.0000x reference)
//
#include <hip/hip_runtime.h>
#include <math.h>

// ---------------------------------------------------------------------------
// Types / helpers
// ---------------------------------------------------------------------------
typedef __bf16 bf16x8 __attribute__((ext_vector_type(8)));
typedef float floatx4 __attribute__((ext_vector_type(4)));

__device__ __forceinline__ unsigned short f32_to_bf16(float f) {
  unsigned int u = __float_as_uint(f);
  u = u + 0x7FFFu + ((u >> 16) & 1u);   // RNE; inputs finite
  return (unsigned short)(u >> 16);
}
__device__ __forceinline__ float bf16_to_f32(unsigned short s) {
  return __uint_as_float(((unsigned int)s) << 16);
}

// async global->LDS, 16B per lane. lds base must be wave-uniform; HW scatters
// lane i to ldsbase + i*16  [m97 pattern].
__device__ __forceinline__ void gld_lds16(const unsigned short* g,
                                          unsigned short* l) {
  __builtin_amdgcn_global_load_lds(
      (const __attribute__((address_space(1))) unsigned int*)g,
      (__attribute__((address_space(3))) unsigned int*)l, 16, 0, 0);
}

// ---------------------------------------------------------------------------
// fp32 -> bf16 cast (vectorized float4 -> ushort4)
// ---------------------------------------------------------------------------
__global__ void cast_kernel(const float* __restrict__ in,
                            unsigned short* __restrict__ out, int n4) {
  int i = blockIdx.x * blockDim.x + threadIdx.x;
  if (i >= n4) return;
  const float4 v = reinterpret_cast<const float4*>(in)[i];
  ushort4 o;
  o.x = f32_to_bf16(v.x); o.y = f32_to_bf16(v.y);
  o.z = f32_to_bf16(v.z); o.w = f32_to_bf16(v.w);
  reinterpret_cast<ushort4*>(out)[i] = o;
}

// 4 equal-size weight casts in one dispatch (blockIdx.y selects buffer)
__global__ void cast4_kernel(const float* __restrict__ a,
                             const float* __restrict__ b,
                             const float* __restrict__ c,
                             const float* __restrict__ d,
                             unsigned short* __restrict__ oa,
                             unsigned short* __restrict__ ob,
                             unsigned short* __restrict__ oc,
                             unsigned short* __restrict__ od, int n4) {
  int i = blockIdx.x * blockDim.x + threadIdx.x;
  if (i >= n4) return;
  const float* in;
  unsigned short* out;
  switch (blockIdx.y) {
    case 0: in = a; out = oa; break;
    case 1: in = b; out = ob; break;
    case 2: in = c; out = oc; break;
    default: in = d; out = od; break;
  }
  const float4 v = reinterpret_cast<const float4*>(in)[i];
  ushort4 o;
  o.x = f32_to_bf16(v.x); o.y = f32_to_bf16(v.y);
  o.z = f32_to_bf16(v.z); o.w = f32_to_bf16(v.w);
  reinterpret_cast<ushort4*>(out)[i] = o;
}

// ---------------------------------------------------------------------------
// RoPE cos/sin table: tab[s*64+i] = (cos, sin) of s / 10000^(i/64)
// ---------------------------------------------------------------------------
__global__ void rope_table_kernel(float2* __restrict__ tab, int total) {
  int idx = blockIdx.x * blockDim.x + threadIdx.x;
  if (idx >= total) return;
  const int s = idx >> 6, i = idx & 63;
  const float inv = powf(10000.0f, -(float)i * (1.0f / 64.0f));
  const float ang = (float)s * inv;
  tab[idx] = make_float2(cosf(ang), sinf(ang));
}

// ---------------------------------------------------------------------------
// 256x256-tile GEMM, BK=64, 512 threads (8 waves: 2M x 4N), K-tile double
// buffer with ONE __syncthreads per tile + 4 advisory-barrier compute phases.
//  - Staging/read swizzle formulas are VERBATIM the verified 128^2 kernel
//    (R5: SQ_LDS_BANK_CONFLICT == 0, numerics stable R0-R5):
//    source chunk (lane%8)^(lane/8), read chunk (ks*4+quad)^(m16&7).
//  - Dataflow: prefetch tile t+1 issued at top of tile t (after the
//    __syncthreads that (a) fences tile t-1's readers off buf[cur^1] and
//    (b) drains vmcnt -> buf[cur] visible). Loads are consumed one full
//    compute-tile (~2500 cy) after issue -> latency hidden, drain free.
//  - Intra-tile raw s_barrier/setprio are scheduling-only: no data dep
//    crosses them, uniform control flow -> cannot introduce races.
//  - Bit-exactness: per output element the K order and MFMA shape match the
//    128^2 kernel exactly -> GEMM result bit-identical.
// MODE 0: single GEMM, fp32 out + bias (O projection).
// MODE 1: z-fused QKV (blockIdx.z: 0=Q rope*scl, 1=K rope, 2=Vt transposed).
// ---------------------------------------------------------------------------
template <int MODE>
__global__ __launch_bounds__(512, 1) void gemm256(
    const unsigned short* __restrict__ A,
    const unsigned short* __restrict__ B0,
    const unsigned short* __restrict__ B1,
    const unsigned short* __restrict__ B2,
    const float* __restrict__ bias0, const float* __restrict__ bias1,
    const float* __restrict__ bias2, float* __restrict__ Cf,
    unsigned short* __restrict__ Cb0, unsigned short* __restrict__ Cb1,
    unsigned short* __restrict__ Cb2, const float2* __restrict__ tab,
    float qscale, int M, int N, int K, int S) {
  __shared__ unsigned short As[2][256 * 64];  // 64 KB
  __shared__ unsigned short Bs[2][256 * 64];  // 64 KB  -> 128 KB total
  const int t = threadIdx.x;
  const int lane = t & 63;
  const int w = t >> 6;          // 0..7
  const int wmh = w >> 2;        // 0..1: M-half of the block tile
  const int wnq = w & 3;         // 0..3: N-quarter
  const int m16 = lane & 15;
  const int quad = lane >> 4;
  const int key = m16 & 7;
  const int z = (MODE == 1) ? blockIdx.z : 0;

  // XCD swizzle per z-slice (nwg = 128, % 8 == 0 -> simple form bijective)
  const int nwg = gridDim.x * gridDim.y;
  const int orig = blockIdx.y * gridDim.x + blockIdx.x;
  const int wgid = (orig & 7) * (nwg >> 3) + (orig >> 3);
  const int bm = (wgid / gridDim.x) * 256;
  const int bn = (wgid % gridDim.x) * 256;

  const unsigned short* B =
      (MODE == 0) ? B0 : ((z == 0) ? B0 : ((z == 1) ? B1 : B2));
  const float* bias =
      (MODE == 0) ? bias0 : ((z == 0) ? bias0 : ((z == 1) ? bias1 : bias2));
  unsigned short* Cb =
      (MODE == 0) ? (unsigned short*)0 : ((z == 0) ? Cb0 : ((z == 1) ? Cb1 : Cb2));
  const float scl = (z == 0) ? qscale : 1.0f;

  // staging geometry (verbatim 128^2 pattern): wave w, call it -> LDS group
  // g = w*4+it (rows g*8..g*8+7); lane -> row g*8 + lane/8, global source
  // chunk (lane%8)^(lane/8)  [XOR pre-swizzle on global address]
  const int lr = lane >> 3;
  const int lc = ((lane & 7) ^ lr) * 8;
  const unsigned short* Ag = A + (size_t)(bm + w * 32 + lr) * K + lc;
  const unsigned short* Bg = B + (size_t)(bn + w * 32 + lr) * K + lc;

  floatx4 acc[8][4];
#pragma unroll
  for (int mi = 0; mi < 8; ++mi)
#pragma unroll
    for (int ni = 0; ni < 4; ++ni) acc[mi][ni] = floatx4{0.f, 0.f, 0.f, 0.f};

  // prologue: stage tile 0 into buffer 0 (8 gld_lds per wave)
#pragma unroll
  for (int it = 0; it < 4; ++it) {
    gld_lds16(Ag + (size_t)it * 8 * K, &As[0][(w * 4 + it) * 512]);
    gld_lds16(Bg + (size_t)it * 8 * K, &Bs[0][(w * 4 + it) * 512]);
  }

  const int nkt = K >> 6;  // 32
  for (int kt = 0; kt < nkt; ++kt) {
    const int cur = kt & 1;
    // (a) all waves done reading buf[cur^1] (tile kt-1) -> safe to overwrite
    // (b) vmcnt drained -> buf[cur] (tile kt, staged one tile ago) visible
    __syncthreads();
    const unsigned short* Ac = &As[cur][0];
    const unsigned short* Bc = &Bs[cur][0];
    unsigned short* An = &As[cur ^ 1][0];
    unsigned short* Bn = &Bs[cur ^ 1][0];
    const bool pf = (kt + 1 < nkt);     // block-uniform
    const int kn = (kt + 1) << 6;

#pragma unroll
    for (int q = 0; q < 4; ++q) {       // 4 compute phases (C quadrants)
      const int mh = q >> 1, nh = q & 1;
      bf16x8 af[4][2], bfr[2][2];
#pragma unroll
      for (int mi = 0; mi < 4; ++mi) {
        const int mrow = wmh * 128 + (mh * 4 + mi) * 16 + m16;
#pragma unroll
        for (int ks = 0; ks < 2; ++ks)
          af[mi][ks] = *reinterpret_cast<const bf16x8*>(
              &Ac[mrow * 64 + (((ks * 4 + quad) ^ key) << 3)]);
      }
#pragma unroll
      for (int ni = 0; ni < 2; ++ni) {
        const int nrow = wnq * 64 + (nh * 2 + ni) * 16 + m16;
#pragma unroll
        for (int ks = 0; ks < 2; ++ks)
          bfr[ni][ks] = *reinterpret_cast<const bf16x8*>(
              &Bc[nrow * 64 + (((ks * 4 + quad) ^ key) << 3)]);
      }
      if (pf) {  // spread next-tile staging: 2 DMAs per phase (8 total)
        gld_lds16(Ag + (size_t)q * 8 * K + kn, &An[(w * 4 + q) * 512]);
        gld_lds16(Bg + (size_t)q * 8 * K + kn, &Bn[(w * 4 + q) * 512]);
      }
      __builtin_amdgcn_s_barrier();     // advisory: phase-align waves
      __builtin_amdgcn_s_setprio(1);
#pragma unroll
      for (int mi = 0; mi < 4; ++mi)
#pragma unroll
        for (int ni = 0; ni < 2; ++ni)
#pragma unroll
          for (int ks = 0; ks < 2; ++ks)
            acc[mh * 4 + mi][nh * 2 + ni] =
                __builtin_amdgcn_mfma_f32_16x16x32_bf16(
                    af[mi][ks], bfr[ni][ks], acc[mh * 4 + mi][nh * 2 + ni],
                    0, 0, 0);
      __builtin_amdgcn_s_setprio(0);
      __builtin_amdgcn_s_barrier();     // advisory
    }
  }

  // epilogue: C/D layout col=lane&15, row=quad*4+reg  [m89/m91 verified]
#pragma unroll
  for (int mi = 0; mi < 8; ++mi) {
    const int rbase = bm + wmh * 128 + mi * 16 + quad * 4;
#pragma unroll
    for (int ni = 0; ni < 4; ++ni) {
      const int col = bn + wnq * 64 + ni * 16 + m16;
      const float bvv = bias[col];
      if (MODE == 0) {
#pragma unroll
        for (int r = 0; r < 4; ++r)
          Cf[(size_t)(rbase + r) * N + col] = acc[mi][ni][r] + bvv;
      } else if (z != 2) {  // RoPE (interleaved pairs) -> bf16, scaled
        const int pi = (col & 127) >> 1;
#pragma unroll
        for (int r = 0; r < 4; ++r) {
          const int row = rbase + r;
          const int s = row & (S - 1);
          const float v = acc[mi][ni][r] + bvv;
          const float vp = __shfl_xor(v, 1);
          const float2 cs = tab[s * 64 + pi];
          const float oe = (v * cs.x - vp * cs.y) * scl;
          const float oo = (vp * cs.x + v * cs.y) * scl;
          if ((m16 & 1) == 0) {
            const unsigned pk =
                (unsigned)f32_to_bf16(oe) | ((unsigned)f32_to_bf16(oo) << 16);
            *reinterpret_cast<unsigned*>(Cb + (size_t)row * N + col) = pk;
          }
        }
      } else {  // transposed bf16 V: Vt[(b*2048 + col)][s]
        const int b = rbase >> 11;           // S = 2048
        const int s = rbase & (S - 1);       // multiple of 4
        ushort4 pk;
        pk.x = f32_to_bf16(acc[mi][ni][0] + bvv);
        pk.y = f32_to_bf16(acc[mi][ni][1] + bvv);
        pk.z = f32_to_bf16(acc[mi][ni][2] + bvv);
        pk.w = f32_to_bf16(acc[mi][ni][3] + bvv);
        *reinterpret_cast<ushort4*>(
            Cb + ((size_t)((b << 11) + col)) * S + s) = pk;
      }
    }
  }
}

// ---------------------------------------------------------------------------
// MFMA flash attention — VERBATIM round-0 kernel (verified: 96 us, bit-exact
// component). DMA/prefetch restaging variants remain banned (R2/R3).
// ---------------------------------------------------------------------------
constexpr int F_BQ = 128, F_BK = 64, F_DH = 128;
constexpr int KS_STR = 136;
constexpr int VS_STR = 72;
constexpr int PS_STR = 72;

__global__ __launch_bounds__(256, 2) void fattn_kernel(
    const unsigned short* __restrict__ Qb, const unsigned short* __restrict__ Kb,
    const unsigned short* __restrict__ Vtb, unsigned short* __restrict__ Ob,
    int S, int H, int nh) {
  __shared__ unsigned short Ks[F_BK * KS_STR];
  __shared__ unsigned short Vts[F_DH * VS_STR];
  __shared__ unsigned short Ps[F_BQ * PS_STR];

  const int t = threadIdx.x;
  const int lane = t & 63;
  const int w = t >> 6;
  const int l15 = lane & 15;
  const int quad = lane >> 4;

  const int i = blockIdx.x;
  const int bh = i & 31;
  const int qt = (i < 256) ? (i >> 5) : (15 - ((i - 256) >> 5));
  const int h = bh & 15;
  const int b = bh >> 4;
  const int q0 = qt * F_BQ;

  const unsigned short* Qrow = Qb + ((size_t)(b * S + q0)) * H + h * F_DH;
  const unsigned short* Krow = Kb + ((size_t)b * S) * H + h * F_DH;
  const unsigned short* Vtrow = Vtb + ((size_t)bh * F_DH) * S;
  unsigned short* Orow = Ob + ((size_t)(b * S + q0)) * H + h * F_DH;

  bf16x8 aq[2][4];
#pragma unroll
  for (int qg = 0; qg < 2; ++qg)
#pragma unroll
    for (int ks = 0; ks < 4; ++ks)
      aq[qg][ks] = *reinterpret_cast<const bf16x8*>(
          Qrow + (size_t)(w * 32 + qg * 16 + l15) * H + ks * 32 + quad * 8);

  floatx4 oacc[2][8];
#pragma unroll
  for (int qg = 0; qg < 2; ++qg)
#pragma unroll
    for (int dj = 0; dj < 8; ++dj) oacc[qg][dj] = floatx4{0.f, 0.f, 0.f, 0.f};
  float lpart[2][4] = {{0.f, 0.f, 0.f, 0.f}, {0.f, 0.f, 0.f, 0.f}};
  int qrow[2][4];
#pragma unroll
  for (int qg = 0; qg < 2; ++qg)
#pragma unroll
    for (int r = 0; r < 4; ++r)
      qrow[qg][r] = q0 + w * 32 + qg * 16 + quad * 4 + r;

  const int ntile = q0 / F_BK + 2;
  for (int tile = 0; tile < ntile; ++tile) {
    const int k0 = tile * F_BK;
    __syncthreads();
    {
      const int kt = t >> 2, c0 = (t & 3) * 32;
      const unsigned short* g = Krow + (size_t)(k0 + kt) * H + c0;
#pragma unroll
      for (int ii = 0; ii < 4; ++ii)
        *reinterpret_cast<uint4*>(&Ks[kt * KS_STR + c0 + ii * 8]) =
            *reinterpret_cast<const uint4*>(g + ii * 8);
    }
    {
      const int d = t >> 1, c0 = (t & 1) * 32;
      const unsigned short* g = Vtrow + (size_t)d * S + k0 + c0;
#pragma unroll
      for (int ii = 0; ii < 4; ++ii)
        *reinterpret_cast<uint4*>(&Vts[d * VS_STR + c0 + ii * 8]) =
            *reinterpret_cast<const uint4*>(g + ii * 8);
    }
    __syncthreads();

    floatx4 sacc[2][4];
#pragma unroll
    for (int qg = 0; qg < 2; ++qg)
#pragma unroll
      for (int j = 0; j < 4; ++j) sacc[qg][j] = floatx4{0.f, 0.f, 0.f, 0.f};
#pragma unroll
    for (int j = 0; j < 4; ++j) {
      bf16x8 bk[4];
#pragma unroll
      for (int ks = 0; ks < 4; ++ks)
        bk[ks] = *reinterpret_cast<const bf16x8*>(
            &Ks[(j * 16 + l15) * KS_STR + ks * 32 + quad * 8]);
#pragma unroll
      for (int qg = 0; qg < 2; ++qg)
#pragma unroll
        for (int ks = 0; ks < 4; ++ks)
          sacc[qg][j] = __builtin_amdgcn_mfma_f32_16x16x32_bf16(
              aq[qg][ks], bk[ks], sacc[qg][j], 0, 0, 0);
    }

#pragma unroll
    for (int qg = 0; qg < 2; ++qg)
#pragma unroll
      for (int j = 0; j < 4; ++j) {
        const int ktg = k0 + j * 16 + l15;
#pragma unroll
        for (int r = 0; r < 4; ++r) {
          const float p =
              (ktg <= qrow[qg][r]) ? exp2f(sacc[qg][j][r]) : 0.0f;
          lpart[qg][r] += p;
          Ps[(w * 32 + qg * 16 + quad * 4 + r) * PS_STR + j * 16 + l15] =
              f32_to_bf16(p);
        }
      }

#pragma unroll
    for (int ks2 = 0; ks2 < 2; ++ks2) {
      bf16x8 ap[2];
#pragma unroll
      for (int qg = 0; qg < 2; ++qg)
        ap[qg] = *reinterpret_cast<const bf16x8*>(
            &Ps[(w * 32 + qg * 16 + l15) * PS_STR + ks2 * 32 + quad * 8]);
#pragma unroll
      for (int dj = 0; dj < 8; ++dj) {
        const bf16x8 bv = *reinterpret_cast<const bf16x8*>(
            &Vts[(dj * 16 + l15) * VS_STR + ks2 * 32 + quad * 8]);
#pragma unroll
        for (int qg = 0; qg < 2; ++qg)
          oacc[qg][dj] = __builtin_amdgcn_mfma_f32_16x16x32_bf16(
              ap[qg], bv, oacc[qg][dj], 0, 0, 0);
      }
    }
  }

#pragma unroll
  for (int qg = 0; qg < 2; ++qg)
#pragma unroll
    for (int r = 0; r < 4; ++r) {
      float l = lpart[qg][r];
      l += __shfl_xor(l, 1);
      l += __shfl_xor(l, 2);
      l += __shfl_xor(l, 4);
      l += __shfl_xor(l, 8);
      const float linv = 1.0f / l;
      unsigned short* orow =
          Orow + (size_t)(w * 32 + qg * 16 + quad * 4 + r) * H;
#pragma unroll
      for (int dj = 0; dj < 8; ++dj)
        orow[dj * 16 + l15] = f32_to_bf16(oacc[qg][dj][r] * linv);
    }
}

// ---------------------------------------------------------------------------
// Launch
// ---------------------------------------------------------------------------
extern "C" void kernel_launch(void* const* d_in, const int* in_sizes, int n_in,
                              void* d_out, int out_size, void* d_ws,
                              size_t ws_size, hipStream_t stream) {
  const float* x  = (const float*)d_in[0];
  const float* Wq = (const float*)d_in[1];
  const float* bq = (const float*)d_in[2];
  const float* Wk = (const float*)d_in[3];
  const float* bk = (const float*)d_in[4];
  const float* Wv = (const float*)d_in[5];
  const float* bv = (const float*)d_in[6];
  const float* Wo = (const float*)d_in[7];
  const float* bo = (const float*)d_in[8];
  float* out = (float*)d_out;

  const int B = 2, S = 2048, H = 2048, nh = 16;
  const int M = B * S;  // 4096

  // workspace layout (~113 MB, no overlays)
  unsigned short* Wqb = (unsigned short*)d_ws;
  unsigned short* Wkb = Wqb + (size_t)H * H;
  unsigned short* Wvb = Wkb + (size_t)H * H;
  unsigned short* Wob = Wvb + (size_t)H * H;
  unsigned short* xb  = Wob + (size_t)H * H;
  unsigned short* Qbb = xb + (size_t)M * H;
  unsigned short* Kbb = Qbb + (size_t)M * H;
  unsigned short* Vtb = Kbb + (size_t)M * H;
  unsigned short* Ob  = Vtb + (size_t)M * H;
  float2* tab = (float2*)(Ob + (size_t)M * H);  // S*64 float2 = 1 MB

  const int cast_w4 = H * H / 4;
  const int cast_x4 = M * H / 4;
  const int tab_n = S * 64;

  rope_table_kernel<<<dim3(tab_n / 256), dim3(256), 0, stream>>>(tab, tab_n);
  cast_kernel<<<dim3(cast_x4 / 256), dim3(256), 0, stream>>>(x, xb, cast_x4);
  cast4_kernel<<<dim3(cast_w4 / 256, 4), dim3(256), 0, stream>>>(
      Wq, Wk, Wv, Wo, Wqb, Wkb, Wvb, Wob, cast_w4);

  const float qscale = 0.08838834764831845f * 1.4426950408889634f;

  // Q, K, V projections: one dispatch, 256^2 tiles: (8, 16, 3) = 384 blocks
  gemm256<1><<<dim3(H / 256, M / 256, 3), dim3(512), 0, stream>>>(
      xb, Wqb, Wkb, Wvb, bq, bk, bv, nullptr, Qbb, Kbb, Vtb, tab, qscale,
      M, H, H, S);

  fattn_kernel<<<dim3((S / F_BQ) * B * nh), dim3(256), 0, stream>>>(
      Qbb, Kbb, Vtb, Ob, S, H, nh);

  // O projection: 256^2 tiles: (8, 16) = 128 blocks, one full round
  gemm256<0><<<dim3(H / 256, M / 256, 1), dim3(512), 0, stream>>>(
      Ob, Wob, nullptr, nullptr, bo, nullptr, nullptr, out, nullptr, nullptr,
      nullptr, nullptr, 1.0f, M, H, H, S);
}

// Round 7
// 410.469 us; speedup vs baseline: 1.1422x; 1.1422x over previous
//
#include <hip/hip_runtime.h>
#include <math.h>

// ---------------------------------------------------------------------------
// Types / helpers
// ---------------------------------------------------------------------------
typedef __bf16 bf16x8 __attribute__((ext_vector_type(8)));
typedef float floatx4 __attribute__((ext_vector_type(4)));

__device__ __forceinline__ unsigned short f32_to_bf16(float f) {
  unsigned int u = __float_as_uint(f);
  u = u + 0x7FFFu + ((u >> 16) & 1u);   // RNE; inputs finite
  return (unsigned short)(u >> 16);
}
__device__ __forceinline__ float bf16_to_f32(unsigned short s) {
  return __uint_as_float(((unsigned int)s) << 16);
}

// async global->LDS, 16B per lane. lds base must be wave-uniform; HW scatters
// lane i to ldsbase + i*16  [m97 pattern].
__device__ __forceinline__ void gld_lds16(const unsigned short* g,
                                          unsigned short* l) {
  __builtin_amdgcn_global_load_lds(
      (const __attribute__((address_space(1))) unsigned int*)g,
      (__attribute__((address_space(3))) unsigned int*)l, 16, 0, 0);
}

// ---------------------------------------------------------------------------
// fp32 -> bf16 cast (vectorized float4 -> ushort4)
// ---------------------------------------------------------------------------
__global__ void cast_kernel(const float* __restrict__ in,
                            unsigned short* __restrict__ out, int n4) {
  int i = blockIdx.x * blockDim.x + threadIdx.x;
  if (i >= n4) return;
  const float4 v = reinterpret_cast<const float4*>(in)[i];
  ushort4 o;
  o.x = f32_to_bf16(v.x); o.y = f32_to_bf16(v.y);
  o.z = f32_to_bf16(v.z); o.w = f32_to_bf16(v.w);
  reinterpret_cast<ushort4*>(out)[i] = o;
}

// 4 equal-size weight casts in one dispatch (blockIdx.y selects buffer)
__global__ void cast4_kernel(const float* __restrict__ a,
                             const float* __restrict__ b,
                             const float* __restrict__ c,
                             const float* __restrict__ d,
                             unsigned short* __restrict__ oa,
                             unsigned short* __restrict__ ob,
                             unsigned short* __restrict__ oc,
                             unsigned short* __restrict__ od, int n4) {
  int i = blockIdx.x * blockDim.x + threadIdx.x;
  if (i >= n4) return;
  const float* in;
  unsigned short* out;
  switch (blockIdx.y) {
    case 0: in = a; out = oa; break;
    case 1: in = b; out = ob; break;
    case 2: in = c; out = oc; break;
    default: in = d; out = od; break;
  }
  const float4 v = reinterpret_cast<const float4*>(in)[i];
  ushort4 o;
  o.x = f32_to_bf16(v.x); o.y = f32_to_bf16(v.y);
  o.z = f32_to_bf16(v.z); o.w = f32_to_bf16(v.w);
  reinterpret_cast<ushort4*>(out)[i] = o;
}

// ---------------------------------------------------------------------------
// RoPE cos/sin table: tab[s*64+i] = (cos, sin) of s / 10000^(i/64)
// ---------------------------------------------------------------------------
__global__ void rope_table_kernel(float2* __restrict__ tab, int total) {
  int idx = blockIdx.x * blockDim.x + threadIdx.x;
  if (idx >= total) return;
  const int s = idx >> 6, i = idx & 63;
  const float inv = powf(10000.0f, -(float)i * (1.0f / 64.0f));
  const float ang = (float)s * inv;
  tab[idx] = make_float2(cosf(ang), sinf(ang));
}

// ---------------------------------------------------------------------------
// Fused GEMM: C[m][n] = sum_k A[m][k]*B[n][k] + bias[n]
// 128x128 tile, BK=64, 4 waves, 4x4 16x16x32, XCD-aware block swizzle.
// EPI=0: fp32 out + bias (used for the O projection).   [VERBATIM R5]
// ---------------------------------------------------------------------------
template <int EPI>
__global__ __launch_bounds__(256) void gemm_fused(
    const unsigned short* __restrict__ A, const unsigned short* __restrict__ B,
    const float* __restrict__ bias, float* __restrict__ Cf,
    unsigned short* __restrict__ Cb, const float2* __restrict__ tab,
    float scl, int M, int N, int K, int S) {
  __shared__ unsigned short As[128 * 64];
  __shared__ unsigned short Bs[128 * 64];
  const int t = threadIdx.x;
  const int lane = t & 63;
  const int w = t >> 6;

  // XCD swizzle: contiguous tile range per XCD (requires nwg % 8 == 0).
  const int nwg = gridDim.x * gridDim.y;       // 512 here
  const int orig = blockIdx.y * gridDim.x + blockIdx.x;
  const int wgid = (orig & 7) * (nwg >> 3) + (orig >> 3);
  const int bm = (wgid / gridDim.x) * 128;
  const int bn = (wgid % gridDim.x) * 128;

  const int wm = (w & 1) * 64;
  const int wn = (w >> 1) * 64;
  const int m16 = lane & 15;
  const int quad = lane >> 4;
  const int key = m16 & 7;

  const int lr = lane >> 3;
  const int lc = ((lane & 7) ^ lr) * 8;

  floatx4 acc[4][4];
#pragma unroll
  for (int i = 0; i < 4; ++i)
#pragma unroll
    for (int j = 0; j < 4; ++j) acc[i][j] = floatx4{0.f, 0.f, 0.f, 0.f};

  const unsigned short* Abase = A + (size_t)(bm + w * 32 + lr) * K + lc;
  const unsigned short* Bbase = B + (size_t)(bn + w * 32 + lr) * K + lc;

  for (int k0 = 0; k0 < K; k0 += 64) {
    __syncthreads();  // previous-iter readers done before overwrite
#pragma unroll
    for (int it = 0; it < 4; ++it) {
      gld_lds16(Abase + (size_t)it * 8 * K + k0, &As[(w * 4 + it) * 512]);
      gld_lds16(Bbase + (size_t)it * 8 * K + k0, &Bs[(w * 4 + it) * 512]);
    }
    __syncthreads();  // drains vmcnt(0): LDS data visible
#pragma unroll
    for (int ks = 0; ks < 64; ks += 32) {
      const int ck = ks >> 3;  // 0 or 4
      bf16x8 af[4], bfr[4];
#pragma unroll
      for (int i = 0; i < 4; ++i)
        af[i] = *reinterpret_cast<const bf16x8*>(
            &As[(wm + i * 16 + m16) * 64 + ((ck | quad) ^ key) * 8]);
#pragma unroll
      for (int j = 0; j < 4; ++j)
        bfr[j] = *reinterpret_cast<const bf16x8*>(
            &Bs[(wn + j * 16 + m16) * 64 + ((ck | quad) ^ key) * 8]);
#pragma unroll
      for (int i = 0; i < 4; ++i)
#pragma unroll
        for (int j = 0; j < 4; ++j)
          acc[i][j] = __builtin_amdgcn_mfma_f32_16x16x32_bf16(
              af[i], bfr[j], acc[i][j], 0, 0, 0);
    }
  }

  // epilogue: C/D layout col=lane&15, row=quad*4+reg  [m89/m91 verified]
#pragma unroll
  for (int i = 0; i < 4; ++i) {
    const int rbase = bm + wm + i * 16 + quad * 4;
#pragma unroll
    for (int j = 0; j < 4; ++j) {
      const int col = bn + wn + j * 16 + m16;
      const float bv = bias[col];
      if (EPI == 0) {
#pragma unroll
        for (int r = 0; r < 4; ++r)
          Cf[(size_t)(rbase + r) * N + col] = acc[i][j][r] + bv;
      }
    }
  }
}

// ---------------------------------------------------------------------------
// QKV fused projection (VERBATIM R5): one dispatch, blockIdx.z in {0,1,2}
// selects {Wq->Q(RoPE,scaled), Wk->K(RoPE), Wv->Vt(transposed bf16)}.
// 1536 blocks; measured 165 us, 0 bank conflicts, deterministic absmax 0.04.
// ---------------------------------------------------------------------------
__global__ __launch_bounds__(256) void gemm_qkv(
    const unsigned short* __restrict__ A, const unsigned short* __restrict__ Bq,
    const unsigned short* __restrict__ Bk, const unsigned short* __restrict__ Bv,
    const float* __restrict__ biasq, const float* __restrict__ biask,
    const float* __restrict__ biasv, unsigned short* __restrict__ Qb,
    unsigned short* __restrict__ Kb, unsigned short* __restrict__ Vtb,
    const float2* __restrict__ tab, float qscale, int M, int N, int K, int S) {
  __shared__ unsigned short As[128 * 64];
  __shared__ unsigned short Bs[128 * 64];
  const int t = threadIdx.x;
  const int lane = t & 63;
  const int w = t >> 6;
  const int z = blockIdx.z;

  // XCD swizzle within the z-slice (512 blocks, % 8 == 0)
  const int nwg = gridDim.x * gridDim.y;
  const int orig = blockIdx.y * gridDim.x + blockIdx.x;
  const int wgid = (orig & 7) * (nwg >> 3) + (orig >> 3);
  const int bm = (wgid / gridDim.x) * 128;
  const int bn = (wgid % gridDim.x) * 128;

  const int wm = (w & 1) * 64;
  const int wn = (w >> 1) * 64;
  const int m16 = lane & 15;
  const int quad = lane >> 4;
  const int key = m16 & 7;

  const int lr = lane >> 3;
  const int lc = ((lane & 7) ^ lr) * 8;

  const unsigned short* B = (z == 0) ? Bq : ((z == 1) ? Bk : Bv);
  const float* bias = (z == 0) ? biasq : ((z == 1) ? biask : biasv);
  unsigned short* Cb = (z == 0) ? Qb : ((z == 1) ? Kb : Vtb);
  const float scl = (z == 0) ? qscale : 1.0f;

  floatx4 acc[4][4];
#pragma unroll
  for (int i = 0; i < 4; ++i)
#pragma unroll
    for (int j = 0; j < 4; ++j) acc[i][j] = floatx4{0.f, 0.f, 0.f, 0.f};

  const unsigned short* Abase = A + (size_t)(bm + w * 32 + lr) * K + lc;
  const unsigned short* Bbase = B + (size_t)(bn + w * 32 + lr) * K + lc;

  for (int k0 = 0; k0 < K; k0 += 64) {
    __syncthreads();
#pragma unroll
    for (int it = 0; it < 4; ++it) {
      gld_lds16(Abase + (size_t)it * 8 * K + k0, &As[(w * 4 + it) * 512]);
      gld_lds16(Bbase + (size_t)it * 8 * K + k0, &Bs[(w * 4 + it) * 512]);
    }
    __syncthreads();
#pragma unroll
    for (int ks = 0; ks < 64; ks += 32) {
      const int ck = ks >> 3;
      bf16x8 af[4], bfr[4];
#pragma unroll
      for (int i = 0; i < 4; ++i)
        af[i] = *reinterpret_cast<const bf16x8*>(
            &As[(wm + i * 16 + m16) * 64 + ((ck | quad) ^ key) * 8]);
#pragma unroll
      for (int j = 0; j < 4; ++j)
        bfr[j] = *reinterpret_cast<const bf16x8*>(
            &Bs[(wn + j * 16 + m16) * 64 + ((ck | quad) ^ key) * 8]);
#pragma unroll
      for (int i = 0; i < 4; ++i)
#pragma unroll
        for (int j = 0; j < 4; ++j)
          acc[i][j] = __builtin_amdgcn_mfma_f32_16x16x32_bf16(
              af[i], bfr[j], acc[i][j], 0, 0, 0);
    }
  }

  // epilogue: C/D layout col=lane&15, row=quad*4+reg  [m89/m91 verified]
#pragma unroll
  for (int i = 0; i < 4; ++i) {
    const int rbase = bm + wm + i * 16 + quad * 4;
#pragma unroll
    for (int j = 0; j < 4; ++j) {
      const int col = bn + wn + j * 16 + m16;
      const float bvv = bias[col];
      if (z != 2) {  // RoPE (interleaved pairs) -> bf16, scaled
        const int pi = (col & 127) >> 1;
#pragma unroll
        for (int r = 0; r < 4; ++r) {
          const int row = rbase + r;
          const int s = row & (S - 1);
          const float v = acc[i][j][r] + bvv;
          const float vp = __shfl_xor(v, 1);
          const float2 cs = tab[s * 64 + pi];
          const float oe = (v * cs.x - vp * cs.y) * scl;
          const float oo = (vp * cs.x + v * cs.y) * scl;
          if ((m16 & 1) == 0) {
            const unsigned pk =
                (unsigned)f32_to_bf16(oe) | ((unsigned)f32_to_bf16(oo) << 16);
            *reinterpret_cast<unsigned*>(Cb + (size_t)row * N + col) = pk;
          }
        }
      } else {  // transposed bf16 V: Vt[(b*2048 + col)][s]
        const int b = rbase >> 11;           // S = 2048
        const int s = rbase & (S - 1);       // multiple of 4
        ushort4 pk;
        pk.x = f32_to_bf16(acc[i][j][0] + bvv);
        pk.y = f32_to_bf16(acc[i][j][1] + bvv);
        pk.z = f32_to_bf16(acc[i][j][2] + bvv);
        pk.w = f32_to_bf16(acc[i][j][3] + bvv);
        *reinterpret_cast<ushort4*>(
            Cb + ((size_t)((b << 11) + col)) * S + s) = pk;
      }
    }
  }
}

// ---------------------------------------------------------------------------
// MFMA flash attention, F_BQ = 64 (bit-exact split of the verified R0/R5
// kernel): each block now covers 64 Q rows (1 qg group per wave instead of
// 2), doubling the grid to 1024 blocks so 3 blocks/CU are co-resident
// (LDS 45 KB) and staging of one block overlaps compute of another. Per-row
// MFMA chain, K-order, P values, l-reduction identical -> output bit-same.
// Staging loops, LDS strides, softmax, PV all VERBATIM otherwise.
// ---------------------------------------------------------------------------
constexpr int F_BQ = 64, F_BK = 64, F_DH = 128;
constexpr int KS_STR = 136;
constexpr int VS_STR = 72;
constexpr int PS_STR = 72;

__global__ __launch_bounds__(256, 3) void fattn_kernel(
    const unsigned short* __restrict__ Qb, const unsigned short* __restrict__ Kb,
    const unsigned short* __restrict__ Vtb, unsigned short* __restrict__ Ob,
    int S, int H, int nh) {
  __shared__ unsigned short Ks[F_BK * KS_STR];   // 17.4 KB
  __shared__ unsigned short Vts[F_DH * VS_STR];  // 18.4 KB
  __shared__ unsigned short Ps[F_BQ * PS_STR];   //  9.2 KB  -> 45 KB total

  const int t = threadIdx.x;
  const int lane = t & 63;
  const int w = t >> 6;
  const int l15 = lane & 15;
  const int quad = lane >> 4;

  // 1024 blocks: bh = i&31; qt 0..15 ascending then 31..16 descending
  // (pairs qt with 31-qt for causal-length tail balance).
  const int i = blockIdx.x;
  const int bh = i & 31;
  const int qt = (i < 512) ? (i >> 5) : (31 - ((i - 512) >> 5));
  const int h = bh & 15;
  const int b = bh >> 4;
  const int q0 = qt * F_BQ;

  const unsigned short* Qrow = Qb + ((size_t)(b * S + q0)) * H + h * F_DH;
  const unsigned short* Krow = Kb + ((size_t)b * S) * H + h * F_DH;
  const unsigned short* Vtrow = Vtb + ((size_t)bh * F_DH) * S;
  unsigned short* Orow = Ob + ((size_t)(b * S + q0)) * H + h * F_DH;

  bf16x8 aq[4];
#pragma unroll
  for (int ks = 0; ks < 4; ++ks)
    aq[ks] = *reinterpret_cast<const bf16x8*>(
        Qrow + (size_t)(w * 16 + l15) * H + ks * 32 + quad * 8);

  floatx4 oacc[8];
#pragma unroll
  for (int dj = 0; dj < 8; ++dj) oacc[dj] = floatx4{0.f, 0.f, 0.f, 0.f};
  float lpart[4] = {0.f, 0.f, 0.f, 0.f};
  int qrow[4];
#pragma unroll
  for (int r = 0; r < 4; ++r) qrow[r] = q0 + w * 16 + quad * 4 + r;

  const int ntile = qt + 1;  // keys <= q0+63 covered exactly
  for (int tile = 0; tile < ntile; ++tile) {
    const int k0 = tile * F_BK;
    __syncthreads();
    {
      const int kt = t >> 2, c0 = (t & 3) * 32;
      const unsigned short* g = Krow + (size_t)(k0 + kt) * H + c0;
#pragma unroll
      for (int ii = 0; ii < 4; ++ii)
        *reinterpret_cast<uint4*>(&Ks[kt * KS_STR + c0 + ii * 8]) =
            *reinterpret_cast<const uint4*>(g + ii * 8);
    }
    {
      const int d = t >> 1, c0 = (t & 1) * 32;
      const unsigned short* g = Vtrow + (size_t)d * S + k0 + c0;
#pragma unroll
      for (int ii = 0; ii < 4; ++ii)
        *reinterpret_cast<uint4*>(&Vts[d * VS_STR + c0 + ii * 8]) =
            *reinterpret_cast<const uint4*>(g + ii * 8);
    }
    __syncthreads();

    floatx4 sacc[4];
#pragma unroll
    for (int j = 0; j < 4; ++j) sacc[j] = floatx4{0.f, 0.f, 0.f, 0.f};
#pragma unroll
    for (int j = 0; j < 4; ++j) {
      bf16x8 bk[4];
#pragma unroll
      for (int ks = 0; ks < 4; ++ks)
        bk[ks] = *reinterpret_cast<const bf16x8*>(
            &Ks[(j * 16 + l15) * KS_STR + ks * 32 + quad * 8]);
#pragma unroll
      for (int ks = 0; ks < 4; ++ks)
        sacc[j] = __builtin_amdgcn_mfma_f32_16x16x32_bf16(
            aq[ks], bk[ks], sacc[j], 0, 0, 0);
    }

#pragma unroll
    for (int j = 0; j < 4; ++j) {
      const int ktg = k0 + j * 16 + l15;
#pragma unroll
      for (int r = 0; r < 4; ++r) {
        const float p = (ktg <= qrow[r]) ? exp2f(sacc[j][r]) : 0.0f;
        lpart[r] += p;
        Ps[(w * 16 + quad * 4 + r) * PS_STR + j * 16 + l15] = f32_to_bf16(p);
      }
    }

#pragma unroll
    for (int ks2 = 0; ks2 < 2; ++ks2) {
      const bf16x8 ap = *reinterpret_cast<const bf16x8*>(
          &Ps[(w * 16 + l15) * PS_STR + ks2 * 32 + quad * 8]);
#pragma unroll
      for (int dj = 0; dj < 8; ++dj) {
        const bf16x8 bv = *reinterpret_cast<const bf16x8*>(
            &Vts[(dj * 16 + l15) * VS_STR + ks2 * 32 + quad * 8]);
        oacc[dj] = __builtin_amdgcn_mfma_f32_16x16x32_bf16(
            ap, bv, oacc[dj], 0, 0, 0);
      }
    }
  }

#pragma unroll
  for (int r = 0; r < 4; ++r) {
    float l = lpart[r];
    l += __shfl_xor(l, 1);
    l += __shfl_xor(l, 2);
    l += __shfl_xor(l, 4);
    l += __shfl_xor(l, 8);
    const float linv = 1.0f / l;
    unsigned short* orow = Orow + (size_t)(w * 16 + quad * 4 + r) * H;
#pragma unroll
    for (int dj = 0; dj < 8; ++dj)
      orow[dj * 16 + l15] = f32_to_bf16(oacc[dj][r] * linv);
  }
}

// ---------------------------------------------------------------------------
// Launch
// ---------------------------------------------------------------------------
extern "C" void kernel_launch(void* const* d_in, const int* in_sizes, int n_in,
                              void* d_out, int out_size, void* d_ws,
                              size_t ws_size, hipStream_t stream) {
  const float* x  = (const float*)d_in[0];
  const float* Wq = (const float*)d_in[1];
  const float* bq = (const float*)d_in[2];
  const float* Wk = (const float*)d_in[3];
  const float* bk = (const float*)d_in[4];
  const float* Wv = (const float*)d_in[5];
  const float* bv = (const float*)d_in[6];
  const float* Wo = (const float*)d_in[7];
  const float* bo = (const float*)d_in[8];
  float* out = (float*)d_out;

  const int B = 2, S = 2048, H = 2048, nh = 16;
  const int M = B * S;  // 4096

  // workspace layout (~113 MB, no overlays)
  unsigned short* Wqb = (unsigned short*)d_ws;
  unsigned short* Wkb = Wqb + (size_t)H * H;
  unsigned short* Wvb = Wkb + (size_t)H * H;
  unsigned short* Wob = Wvb + (size_t)H * H;
  unsigned short* xb  = Wob + (size_t)H * H;
  unsigned short* Qbb = xb + (size_t)M * H;
  unsigned short* Kbb = Qbb + (size_t)M * H;
  unsigned short* Vtb = Kbb + (size_t)M * H;
  unsigned short* Ob  = Vtb + (size_t)M * H;
  float2* tab = (float2*)(Ob + (size_t)M * H);  // S*64 float2 = 1 MB

  const int cast_w4 = H * H / 4;
  const int cast_x4 = M * H / 4;
  const int tab_n = S * 64;

  rope_table_kernel<<<dim3(tab_n / 256), dim3(256), 0, stream>>>(tab, tab_n);
  cast_kernel<<<dim3(cast_x4 / 256), dim3(256), 0, stream>>>(x, xb, cast_x4);
  cast4_kernel<<<dim3(cast_w4 / 256, 4), dim3(256), 0, stream>>>(
      Wq, Wk, Wv, Wo, Wqb, Wkb, Wvb, Wob, cast_w4);

  const float qscale = 0.08838834764831845f * 1.4426950408889634f;

  // Q, K, V projections in ONE dispatch: (16, 32, 3) = 1536 blocks
  gemm_qkv<<<dim3(H / 128, M / 128, 3), dim3(256), 0, stream>>>(
      xb, Wqb, Wkb, Wvb, bq, bk, bv, Qbb, Kbb, Vtb, tab, qscale, M, H, H, S);

  // 1024 blocks: (S/64) * B * nh / ... = 32 qt * 32 bh
  fattn_kernel<<<dim3((S / F_BQ) * B * nh), dim3(256), 0, stream>>>(
      Qbb, Kbb, Vtb, Ob, S, H, nh);

  gemm_fused<0><<<dim3(H / 128, M / 128), dim3(256), 0, stream>>>(
      Ob, Wob, bo, out, nullptr, nullptr, 1.0f, M, H, H, S);
}